// Round 14
// baseline (115.293 us; speedup 1.0000x reference)
//
#include <hip/hip_runtime.h>
#include <hip/hip_bf16.h>
#include <math.h>

// NT-Xent loss. N=8192 rows, D=256. Two dispatches:
//   k_prep  : row L2-norm fp32->bf16 (ws), posv[i] = (1-pos_i)/T, zero sumexp
//   k_simfin: per-tile symmetric sim kernel + last-block finisher -> out[0].
// SESSION LEDGER (per-strip period): R5 per-tile no-sym 2.95us | R6 per-tile
//   +sym 2.7us (symmetry ~free!) | R7-R16 strip-balanced walk 5.0-6.4us.
//   The R7 "balanced persistent walk" (runtime tile decode, boundary
//   branches, mid-stream LOAD_A) DOUBLED the per-strip period -- it was the
//   mis-attributed regression all along. R6's only flaw was quantization:
//   528 blocks on 512 co-resident slots -> 16 leftover tiles cost a full
//   21.8us second round.
// R17: R6 body (fixed rt/cs per block, jt loop, A loaded once) + fine-
//   grained round 2: grid 640 = 512 one-tile blocks + 128 one-strip blocks
//   (the 16 leftover tiles split 8 ways). Round 2 ~ one strip period (~4us)
//   instead of a tile. Keep R14's fused finisher + posv (launch-gap win).
#define N_ROWS 8192
#define D_DIM  256
#define HALF_N 4096
#define NBLK   640u
#define INV_T      14.285714285714286f      // 1/0.07
#define SCALE_LOG2 20.609929155556620f      // log2(e)/0.07
#define NEG_SCALE  -20.609929155556620f
#define EPSV   1e-8f

typedef __attribute__((ext_vector_type(8))) short bf16x8;   // 8 bf16 = 4 VGPR
typedef __attribute__((ext_vector_type(4))) float f32x4;

#define AS1 __attribute__((address_space(1)))
#define AS3 __attribute__((address_space(3)))
#define AGT __HIP_MEMORY_SCOPE_AGENT

__device__ unsigned g_done = 0;    // k_simfin arrivals (monotonic forever;
                                   // % NBLK == NBLK-1 selects last/iter)

__device__ inline unsigned short f2bf(float x) {
    unsigned int u = __float_as_uint(x);
    unsigned int r = (u + 0x7fffu + ((u >> 16) & 1u)) >> 16;   // RNE
    return (unsigned short)r;
}

// ------- kernel 1: normalize -> bf16; posv; zero sumexp --------------------
__global__ __launch_bounds__(256) void k_prep(const float* __restrict__ feat,
                                              unsigned short* __restrict__ fbf,
                                              float* __restrict__ sumexp,
                                              float* __restrict__ posv) {
    const int tid = threadIdx.x, w = tid >> 6, lane = tid & 63;
    const int row = blockIdx.x * 4 + w;              // 2048 blocks * 4 rows
    const int pc  = (row + HALF_N) & (N_ROWS - 1);

    const float4 v = ((const float4*)(feat + row * D_DIM))[lane];
    const float4 c = ((const float4*)(feat + pc  * D_DIM))[lane];
    float ss  = v.x*v.x + v.y*v.y + v.z*v.z + v.w*v.w;   // ||a||^2
    float dab = v.x*c.x + v.y*c.y + v.z*c.z + v.w*c.w;
    float dbb = c.x*c.x + c.y*c.y + c.z*c.z + c.w*c.w;
    #pragma unroll
    for (int off = 32; off; off >>= 1) {
        ss  += __shfl_xor(ss,  off);
        dab += __shfl_xor(dab, off);
        dbb += __shfl_xor(dbb, off);
    }
    const float na = fmaxf(sqrtf(ss), EPSV);
    const float sc = 1.f / na;
    ushort4 o;
    o.x = f2bf(v.x * sc); o.y = f2bf(v.y * sc);
    o.z = f2bf(v.z * sc); o.w = f2bf(v.w * sc);
    ((ushort4*)(fbf + row * D_DIM))[lane] = o;
    if (lane == 0)
        posv[row] = INV_T - (dab / (na * fmaxf(sqrtf(dbb), EPSV))) * INV_T;
    if (tid < 4) sumexp[blockIdx.x * 4 + tid] = 0.f;
}

// ------- kernel 2: per-tile sim + exp + row/col sums + finisher ------------
// Tiles: 528 upper-triangle 256x256 (rt >= cs) of the 8192^2 sim matrix.
// Blocks 0..511: tile tt = blockIdx, strips jt = 0..7 (R6 structure: rt/cs
// loop-invariant, A loaded ONCE into 128 VGPR, 16 KB B strip via
// global_load_lds w=16 XOR-16B-chunk swizzle, DMA(jt+1) overlaps epilogue).
// Blocks 512..639: single strip (tile 512+((b-512)>>3), jt=(b-512)&7) --
// the fine-grained second round (~1 strip period instead of a whole tile).
// Off-diag epilogue: rsum in regs + csum per strip (shfl over q + atomic).
// Diag: full tile, true diagonal masked, rsum only.
// Tail: last arriving block (g_done, ACQ_REL) sums posv+log(sumexp) -> out.
__global__ __launch_bounds__(256, 2) void k_simfin(const unsigned short* __restrict__ fbf,
                                                   float* __restrict__ sumexp,
                                                   const float* __restrict__ posv,
                                                   float* __restrict__ out) {
    __shared__ __align__(16) char Bs[16384];
    __shared__ float red[4];
    __shared__ int lastBlk;
    const int tid  = threadIdx.x;
    const int lane = tid & 63;
    const int w    = tid >> 6;
    const int q    = lane >> 4, l15 = lane & 15;
    const int b    = blockIdx.x;

    int tt, jtBegin, jtEnd;
    if (b < 512) { tt = b;                      jtBegin = 0;            jtEnd = 8; }
    else         { tt = 512 + ((b - 512) >> 3); jtBegin = (b - 512) & 7; jtEnd = jtBegin + 1; }

    // decode tile: tt -> (rt, cs), rt >= cs  (32 row-tiles of 256)
    int rt = (int)((sqrtf(8.f * (float)tt + 1.f) - 1.f) * 0.5f);
    while ((rt + 1) * (rt + 2) / 2 <= tt) ++rt;
    while (rt * (rt + 1) / 2 > tt) --rt;
    const int cs = tt - rt * (rt + 1) / 2;
    const bool isDiag = (rt == cs);
    const int rowBase = rt * 256 + w * 64;

#define STAGE(colRow0) do {                                                   \
        const char* Bg_ = (const char*)fbf + (size_t)(colRow0) * 512;         \
        _Pragma("unroll")                                                     \
        for (int i_ = 0; i_ < 4; ++i_) {                                      \
            const int idx_ = i_ * 256 + tid;                                  \
            const int col_ = idx_ >> 5;                                       \
            const int cir_ = idx_ & 31;                                       \
            __builtin_amdgcn_global_load_lds(                                 \
                (const AS1 void*)(Bg_ + col_ * 512 + ((cir_ ^ (col_ & 7)) << 4)), \
                (AS3 void*)(Bs + idx_ * 16), 16, 0, 0);                       \
        }                                                                     \
    } while (0)

    // A fragments: rows rowBase + ri*16 + l15, k = t*32 + q*8  (128 VGPR)
    bf16x8 afrag[8][4];
    #pragma unroll
    for (int t = 0; t < 8; ++t)
        #pragma unroll
        for (int ri = 0; ri < 4; ++ri)
            afrag[t][ri] = *(const bf16x8*)(fbf + (rowBase + ri*16 + l15) * D_DIM
                                                + t*32 + q*8);

    float rsum[4][4];
    #pragma unroll
    for (int ri = 0; ri < 4; ++ri)
        #pragma unroll
        for (int r = 0; r < 4; ++r) rsum[ri][r] = 0.f;

    STAGE(cs * 256 + jtBegin * 32);

    for (int jt = jtBegin; jt < jtEnd; ++jt) {
        const int colBase = cs * 256 + jt * 32;

        __syncthreads();                           // DMA of strip jt drained

        f32x4 acc[4][2];
        #pragma unroll
        for (int ri = 0; ri < 4; ++ri)
            #pragma unroll
            for (int ci = 0; ci < 2; ++ci) acc[ri][ci] = (f32x4){0.f, 0.f, 0.f, 0.f};

        #pragma unroll
        for (int t = 0; t < 8; ++t) {
            bf16x8 bfrag[2];
            #pragma unroll
            for (int ci = 0; ci < 2; ++ci) {
                const int c   = ci * 16 + l15;     // local col 0..31
                const int cir = t * 4 + q;         // k-chunk
                bfrag[ci] = *(const bf16x8*)(Bs + c * 512 + ((cir ^ (c & 7)) << 4));
            }
            #pragma unroll
            for (int ri = 0; ri < 4; ++ri)
                #pragma unroll
                for (int ci = 0; ci < 2; ++ci)
                    acc[ri][ci] = __builtin_amdgcn_mfma_f32_16x16x32_bf16(
                        afrag[t][ri], bfrag[ci], acc[ri][ci], 0, 0, 0);
        }

        // B consumed; DMA next strip so it overlaps the exp epilogue
        if (jt + 1 < jtEnd) {
            __syncthreads();                       // all waves done reading Bs
            STAGE(cs * 256 + (jt + 1) * 32);
        }

        // epilogue: e = exp2(acc*S - S). C/D layout: col=l15, row=q*4+reg.
        if (isDiag) {
            #pragma unroll
            for (int ri = 0; ri < 4; ++ri) {
                const int trow = rowBase + ri * 16;
                #pragma unroll
                for (int ci = 0; ci < 2; ++ci) {
                    const int tcol = colBase + ci * 16;
                    if (trow == tcol) {            // diagonal 16x16 tile
                        #pragma unroll
                        for (int r = 0; r < 4; ++r) {
                            const float e = __builtin_amdgcn_exp2f(
                                __builtin_fmaf(acc[ri][ci][r], SCALE_LOG2, NEG_SCALE));
                            rsum[ri][r] += (q * 4 + r == l15) ? 0.f : e;
                        }
                    } else {
                        #pragma unroll
                        for (int r = 0; r < 4; ++r)
                            rsum[ri][r] += __builtin_amdgcn_exp2f(
                                __builtin_fmaf(acc[ri][ci][r], SCALE_LOG2, NEG_SCALE));
                    }
                }
            }
        } else {
            // off-diagonal (rt > cs): rsum for rows AND csum for cols
            float csum0 = 0.f, csum1 = 0.f;
            #pragma unroll
            for (int ri = 0; ri < 4; ++ri) {
                #pragma unroll
                for (int r = 0; r < 4; ++r) {
                    const float e0 = __builtin_amdgcn_exp2f(
                        __builtin_fmaf(acc[ri][0][r], SCALE_LOG2, NEG_SCALE));
                    const float e1 = __builtin_amdgcn_exp2f(
                        __builtin_fmaf(acc[ri][1][r], SCALE_LOG2, NEG_SCALE));
                    rsum[ri][r] += e0 + e1;
                    csum0 += e0;
                    csum1 += e1;
                }
            }
            // reduce csum over the 4 q-groups (tile rows live across q)
            csum0 += __shfl_xor(csum0, 16); csum0 += __shfl_xor(csum0, 32);
            csum1 += __shfl_xor(csum1, 16); csum1 += __shfl_xor(csum1, 32);
            if (q == 0)      atomicAdd(&sumexp[colBase      + l15], csum0);
            else if (q == 1) atomicAdd(&sumexp[colBase + 16 + l15], csum1);
        }
    }

    // flush row sums (reduce 16 cols per quad, one atomic per row-group)
    #pragma unroll
    for (int ri = 0; ri < 4; ++ri)
        #pragma unroll
        for (int r = 0; r < 4; ++r) {
            float s = rsum[ri][r];
            s += __shfl_xor(s, 1);
            s += __shfl_xor(s, 2);
            s += __shfl_xor(s, 4);
            s += __shfl_xor(s, 8);
            if (l15 == 0)
                atomicAdd(&sumexp[rowBase + ri * 16 + q * 4 + r], s);
        }
#undef STAGE

    // ---- finisher: last arriving block computes the mean -----------------
    __syncthreads();                               // drain this block's atomics
    if (tid == 0) {
        const unsigned old = __hip_atomic_fetch_add(&g_done, 1u, __ATOMIC_ACQ_REL, AGT);
        lastBlk = ((old % NBLK) == NBLK - 1u);
    }
    __syncthreads();
    if (lastBlk) {
        // acquire above: all prior blocks' sumexp atomics visible; L1
        // invalidated -> plain loads fresh (R13/R14-proven, absmax 0.0).
        float wsum = 0.f;
        for (int i = tid; i < N_ROWS; i += 256)
            wsum += posv[i] + logf(sumexp[i]);
        #pragma unroll
        for (int off = 32; off; off >>= 1) wsum += __shfl_xor(wsum, off);
        if (lane == 0) red[w] = wsum;
        __syncthreads();
        if (tid == 0)
            out[0] = (red[0] + red[1] + red[2] + red[3]) * (1.f / N_ROWS);
    }
}

extern "C" void kernel_launch(void* const* d_in, const int* in_sizes, int n_in,
                              void* d_out, int out_size, void* d_ws, size_t ws_size,
                              hipStream_t stream) {
    const float* feat = (const float*)d_in[0];
    char* ws = (char*)d_ws;
    unsigned short* fbf = (unsigned short*)ws;                       // 4 MB bf16
    float* sumexp = (float*)(ws + 4u * 1024u * 1024u);               // 32 KB
    float* posv   = (float*)(ws + 4u * 1024u * 1024u + 32768u);      // 32 KB

    k_prep  <<<N_ROWS / 4, 256, 0, stream>>>(feat, fbf, sumexp, posv);
    k_simfin<<<NBLK,       256, 0, stream>>>(fbf, sumexp, posv, (float*)d_out);
}

// Round 15
// 105.754 us; speedup vs baseline: 1.0902x; 1.0902x over previous
//
#include <hip/hip_runtime.h>
#include <hip/hip_bf16.h>
#include <math.h>

// NT-Xent loss. N=8192 rows, D=256. THREE dispatches:
//   k_prep: row L2-norm fp32->bf16 (ws), posv[i]=(1-pos_i)/T, zero sumexp
//   k_sim : R7's hot loop, character-for-character (measured 41.5us twice)
//   k_fin : <<<1,256>>> sums posv[i]+log(sumexp[i]) -> out[0] (plain store)
// SESSION LEDGER: every kernel carrying the fused finisher tail pays
//   +11-14us on the SAME body (41.5->52.4 walk R9->R14; <=43.6->57.5
//   per-tile R6->R17) with occupancy 24->13% and VGPR 116->124+: the
//   logf/lastBlk tail globally degrades the hot loop's regalloc/schedule
//   (compiler fragility, also seen R4/R13). Marginal dispatch gap in the
//   R14-era accounting is only ~3-4us, so un-fusing the finisher is net
//   positive: R18 = R14's decomposition wins (posv precompute, no k_nll
//   pass over sim data) + R7's pristine hot kernel + tiny k_fin.
// Totals: R3 131.9 | R9 123.8 | R14 107.9 (prev best) | R17 115.3.
#define N_ROWS 8192
#define D_DIM  256
#define HALF_N 4096
#define INV_T      14.285714285714286f      // 1/0.07
#define SCALE_LOG2 20.609929155556620f      // log2(e)/0.07
#define NEG_SCALE  -20.609929155556620f
#define EPSV   1e-8f

typedef __attribute__((ext_vector_type(8))) short bf16x8;   // 8 bf16 = 4 VGPR
typedef __attribute__((ext_vector_type(4))) float f32x4;

#define AS1 __attribute__((address_space(1)))
#define AS3 __attribute__((address_space(3)))

__device__ inline unsigned short f2bf(float x) {
    unsigned int u = __float_as_uint(x);
    unsigned int r = (u + 0x7fffu + ((u >> 16) & 1u)) >> 16;   // RNE
    return (unsigned short)r;
}

// ------- kernel 1: normalize -> bf16; posv; zero sumexp --------------------
__global__ __launch_bounds__(256) void k_prep(const float* __restrict__ feat,
                                              unsigned short* __restrict__ fbf,
                                              float* __restrict__ sumexp,
                                              float* __restrict__ posv) {
    const int tid = threadIdx.x, w = tid >> 6, lane = tid & 63;
    const int row = blockIdx.x * 4 + w;              // 2048 blocks * 4 rows
    const int pc  = (row + HALF_N) & (N_ROWS - 1);

    const float4 v = ((const float4*)(feat + row * D_DIM))[lane];
    const float4 c = ((const float4*)(feat + pc  * D_DIM))[lane];
    float ss  = v.x*v.x + v.y*v.y + v.z*v.z + v.w*v.w;   // ||a||^2
    float dab = v.x*c.x + v.y*c.y + v.z*c.z + v.w*c.w;
    float dbb = c.x*c.x + c.y*c.y + c.z*c.z + c.w*c.w;
    #pragma unroll
    for (int off = 32; off; off >>= 1) {
        ss  += __shfl_xor(ss,  off);
        dab += __shfl_xor(dab, off);
        dbb += __shfl_xor(dbb, off);
    }
    const float na = fmaxf(sqrtf(ss), EPSV);
    const float sc = 1.f / na;
    ushort4 o;
    o.x = f2bf(v.x * sc); o.y = f2bf(v.y * sc);
    o.z = f2bf(v.z * sc); o.w = f2bf(v.w * sc);
    ((ushort4*)(fbf + row * D_DIM))[lane] = o;
    if (lane == 0)
        posv[row] = INV_T - (dab / (na * fmaxf(sqrtf(dbb), EPSV))) * INV_T;
    if (tid < 4) sumexp[blockIdx.x * 4 + tid] = 0.f;
}

// ------- kernel 2: R7 k_sim, character-for-character -----------------------
// Work unit = strip (tile tt, jt): 256 rows x 32 cols, tt over the 528
// upper-triangle 256x256 tiles (rt >= cs), jt in [0,8). 4224 strips total,
// block b owns strips [(33b)>>2, (33(b+1))>>2)  (8 or 9; spans <= 2 tiles).
// 4 waves x 64 rows; A (64x256) in regs (128 VGPR). Per strip: 16 KB B via
// global_load_lds w=16 XOR-16B-chunk swizzle (conflict-free ds_read_b128),
// 16 ds_read + 64 MFMA per wave, DMA(next strip) before the exp epilogue.
// Off-diag: rsum[r] in regs + csum[c] per strip (shfl over q + atomicAdd).
// Diag: full tile, diagonal masked, row sums only.
__global__ __launch_bounds__(256, 2) void k_sim(const unsigned short* __restrict__ fbf,
                                                float* __restrict__ sumexp) {
    __shared__ __align__(16) char Bs[16384];
    const int tid  = threadIdx.x;
    const int lane = tid & 63;
    const int w    = tid >> 6;
    const int q    = lane >> 4, l15 = lane & 15;

    int g          = (33 * blockIdx.x) >> 2;          // first strip
    const int gEnd = (33 * (blockIdx.x + 1)) >> 2;    // one past last

    // decode tile of strip g: tt -> (rt, cs), rt >= cs
    const int tt0 = g >> 3;
    int rt = (int)((sqrtf(8.f * (float)tt0 + 1.f) - 1.f) * 0.5f);
    while ((rt + 1) * (rt + 2) / 2 <= tt0) ++rt;
    while (rt * (rt + 1) / 2 > tt0) --rt;
    int cs = tt0 - rt * (rt + 1) / 2;
    int jt = g & 7;

#define STAGE(colRow0) do {                                                   \
        const char* Bg_ = (const char*)fbf + (size_t)(colRow0) * 512;         \
        _Pragma("unroll")                                                     \
        for (int i_ = 0; i_ < 4; ++i_) {                                      \
            const int idx_ = i_ * 256 + tid;                                  \
            const int col_ = idx_ >> 5;                                       \
            const int cir_ = idx_ & 31;                                       \
            __builtin_amdgcn_global_load_lds(                                 \
                (const AS1 void*)(Bg_ + col_ * 512 + ((cir_ ^ (col_ & 7)) << 4)), \
                (AS3 void*)(Bs + idx_ * 16), 16, 0, 0);                       \
        }                                                                     \
    } while (0)

    bf16x8 afrag[8][4];
#define LOAD_A(rt_) do {                                                      \
        const int rowBase_ = (rt_) * 256 + w * 64;                            \
        _Pragma("unroll")                                                     \
        for (int t_ = 0; t_ < 8; ++t_)                                        \
            _Pragma("unroll")                                                 \
            for (int ri_ = 0; ri_ < 4; ++ri_)                                 \
                afrag[t_][ri_] = *(const bf16x8*)(fbf                         \
                    + (rowBase_ + ri_*16 + l15) * D_DIM + t_*32 + q*8);       \
    } while (0)

    float rsum[4][4];
#define ZERO_RSUM() do {                                                      \
        _Pragma("unroll")                                                     \
        for (int ri_ = 0; ri_ < 4; ++ri_)                                     \
            _Pragma("unroll")                                                 \
            for (int r_ = 0; r_ < 4; ++r_) rsum[ri_][r_] = 0.f;               \
    } while (0)

#define FLUSH_RSUM(rt_) do {                                                  \
        const int rowBase_ = (rt_) * 256 + w * 64;                            \
        _Pragma("unroll")                                                     \
        for (int ri_ = 0; ri_ < 4; ++ri_)                                     \
            _Pragma("unroll")                                                 \
            for (int r_ = 0; r_ < 4; ++r_) {                                  \
                float s_ = rsum[ri_][r_];                                     \
                s_ += __shfl_xor(s_, 1);                                      \
                s_ += __shfl_xor(s_, 2);                                      \
                s_ += __shfl_xor(s_, 4);                                      \
                s_ += __shfl_xor(s_, 8);                                      \
                if (l15 == 0)                                                 \
                    atomicAdd(&sumexp[rowBase_ + ri_ * 16 + q * 4 + r_], s_); \
            }                                                                 \
    } while (0)

    // prologue: DMA strip g, A for its tile
    STAGE(cs * 256 + jt * 32);
    LOAD_A(rt);
    ZERO_RSUM();

    while (true) {
        const int colBase = cs * 256 + jt * 32;
        const bool isDiag = (rt == cs);
        const int rowBase = rt * 256 + w * 64;

        __syncthreads();                           // DMA of strip g drained

        f32x4 acc[4][2];
        #pragma unroll
        for (int ri = 0; ri < 4; ++ri)
            #pragma unroll
            for (int ci = 0; ci < 2; ++ci) acc[ri][ci] = (f32x4){0.f, 0.f, 0.f, 0.f};

        #pragma unroll
        for (int t = 0; t < 8; ++t) {
            bf16x8 bfrag[2];
            #pragma unroll
            for (int ci = 0; ci < 2; ++ci) {
                const int c   = ci * 16 + l15;     // local col 0..31
                const int cir = t * 4 + q;         // k-chunk
                bfrag[ci] = *(const bf16x8*)(Bs + c * 512 + ((cir ^ (c & 7)) << 4));
            }
            #pragma unroll
            for (int ri = 0; ri < 4; ++ri)
                #pragma unroll
                for (int ci = 0; ci < 2; ++ci)
                    acc[ri][ci] = __builtin_amdgcn_mfma_f32_16x16x32_bf16(
                        afrag[t][ri], bfrag[ci], acc[ri][ci], 0, 0, 0);
        }

        // advance coordinates for strip g+1
        const bool more = (g + 1 < gEnd);
        int nrt = rt, ncs = cs, njt = jt + 1;
        if (njt == 8) {
            njt = 0; ncs = cs + 1;
            if (ncs > rt) { nrt = rt + 1; ncs = 0; }
        }

        // B consumed; DMA next strip so it overlaps the exp epilogue
        if (more) {
            __syncthreads();                       // all waves done reading Bs
            STAGE(ncs * 256 + njt * 32);
            // tile change: issue afrag reload now, latency hides under exp
            if (njt == 0) LOAD_A(nrt);
        }

        // epilogue: e = exp2(acc*S - S). C/D layout: col=l15, row=q*4+reg.
        if (isDiag) {
            #pragma unroll
            for (int ri = 0; ri < 4; ++ri) {
                const int trow = rowBase + ri * 16;
                #pragma unroll
                for (int ci = 0; ci < 2; ++ci) {
                    const int tcol = colBase + ci * 16;
                    if (trow == tcol) {            // diagonal 16x16 tile
                        #pragma unroll
                        for (int r = 0; r < 4; ++r) {
                            const float e = __builtin_amdgcn_exp2f(
                                __builtin_fmaf(acc[ri][ci][r], SCALE_LOG2, NEG_SCALE));
                            rsum[ri][r] += (q * 4 + r == l15) ? 0.f : e;
                        }
                    } else {
                        #pragma unroll
                        for (int r = 0; r < 4; ++r)
                            rsum[ri][r] += __builtin_amdgcn_exp2f(
                                __builtin_fmaf(acc[ri][ci][r], SCALE_LOG2, NEG_SCALE));
                    }
                }
            }
        } else {
            // off-diagonal (rt > cs): rsum for rows AND csum for cols
            float csum0 = 0.f, csum1 = 0.f;
            #pragma unroll
            for (int ri = 0; ri < 4; ++ri) {
                #pragma unroll
                for (int r = 0; r < 4; ++r) {
                    const float e0 = __builtin_amdgcn_exp2f(
                        __builtin_fmaf(acc[ri][0][r], SCALE_LOG2, NEG_SCALE));
                    const float e1 = __builtin_amdgcn_exp2f(
                        __builtin_fmaf(acc[ri][1][r], SCALE_LOG2, NEG_SCALE));
                    rsum[ri][r] += e0 + e1;
                    csum0 += e0;
                    csum1 += e1;
                }
            }
            // reduce csum over the 4 q-groups (block rows live across q)
            csum0 += __shfl_xor(csum0, 16); csum0 += __shfl_xor(csum0, 32);
            csum1 += __shfl_xor(csum1, 16); csum1 += __shfl_xor(csum1, 32);
            if (q == 0)      atomicAdd(&sumexp[colBase      + l15], csum0);
            else if (q == 1) atomicAdd(&sumexp[colBase + 16 + l15], csum1);
        }

        if (!more) break;
        if (njt == 0) {                            // crossed a tile boundary
            FLUSH_RSUM(rt);
            ZERO_RSUM();
        }
        rt = nrt; cs = ncs; jt = njt; ++g;
    }

    FLUSH_RSUM(rt);
#undef STAGE
#undef LOAD_A
#undef ZERO_RSUM
#undef FLUSH_RSUM
}

// ------- kernel 3: tiny finisher -------------------------------------------
__global__ __launch_bounds__(256) void k_fin(const float* __restrict__ sumexp,
                                             const float* __restrict__ posv,
                                             float* __restrict__ out) {
    __shared__ float red[4];
    const int tid = threadIdx.x, w = tid >> 6, lane = tid & 63;
    float wsum = 0.f;
    for (int i = tid; i < N_ROWS; i += 256)
        wsum += posv[i] + logf(sumexp[i]);
    #pragma unroll
    for (int off = 32; off; off >>= 1) wsum += __shfl_xor(wsum, off);
    if (lane == 0) red[w] = wsum;
    __syncthreads();
    if (tid == 0)
        out[0] = (red[0] + red[1] + red[2] + red[3]) * (1.f / N_ROWS);
}

extern "C" void kernel_launch(void* const* d_in, const int* in_sizes, int n_in,
                              void* d_out, int out_size, void* d_ws, size_t ws_size,
                              hipStream_t stream) {
    const float* feat = (const float*)d_in[0];
    char* ws = (char*)d_ws;
    unsigned short* fbf = (unsigned short*)ws;                       // 4 MB bf16
    float* sumexp = (float*)(ws + 4u * 1024u * 1024u);               // 32 KB
    float* posv   = (float*)(ws + 4u * 1024u * 1024u + 32768u);      // 32 KB

    k_prep<<<N_ROWS / 4, 256, 0, stream>>>(feat, fbf, sumexp, posv);
    k_sim <<<512,        256, 0, stream>>>(fbf, sumexp);
    k_fin <<<1,          256, 0, stream>>>(sumexp, posv, (float*)d_out);
}